// Round 9
// baseline (224.524 us; speedup 1.0000x reference)
//
#include <hip/hip_runtime.h>
#include <math.h>
#include <stdint.h>

// Problem constants (B=4, S=4096, H=4096, E=64, top_k=8)
#define TOKENS 16384   // B*S
#define HDIM   4096
#define NEXP   64
#define TOPK   8

#define BM 16          // tokens per block
#define BK 32          // K-chunk
#define CHUNKS (HDIM / BK)

typedef double f64x4 __attribute__((ext_vector_type(4)));

// ---- fp64-MFMA GEMM, global_load_lds staging + raw barrier (T3 2-phase) ----
// logits[t][e] = dot(hidden[t][:], weight[e][:]); fp64 accumulation via
// v_mfma_f64_16x16x4f64 => top-k ordering matches the fp64 numpy reference.
//
// Rounds 4-8 were pinned at 57-61% MfmaUtil across occupancy/pipeline/chunk
// probes. Diagnosis (per m97): __syncthreads() drains vmcnt(0) -> every
// barrier kills the in-flight prefetch. This round: stage direct-to-LDS via
// __builtin_amdgcn_global_load_lds (no reg round-trip, no ds_writes) and use
// raw s_barrier with hand-placed s_waitcnt: loads for chunk c+1 are issued at
// the TOP of chunk c, drained only at the END of chunk c (~2048 pipe-cycles
// of MFMA shadow per SIMD).
//
// LDS layout (both-sides swizzle, rule #21): S[buf] = 2560 floats,
//   A region words [0,512):    element (row,k) at 32*row + 4*((k>>2)^(row&7)) + (k&3)
//   B region words [512,2560): element (e,k)  at 512 + 32*e + 4*((k>>2)^(e&7)) + (k&3)
// global_load_lds writes linearly (base + lane*16B), so the swizzle is applied
// by permuting the per-lane GLOBAL source address; compute reads apply the
// same XOR -> 32 distinct banks per instruction, 2-way max (free, m136).
// C/D layout self-calibrated by probe MFMAs (any bijective layout works).
__global__ __launch_bounds__(256) void router_gemm_mfma(const float* __restrict__ hid,
                                                        const float* __restrict__ wgt,
                                                        float* __restrict__ logits) {
    __shared__ float S[2][2560];   // 2 x 10 KB = 20 KB -> 4+ blocks/CU

    const int tid  = threadIdx.x;
    const int bm   = blockIdx.x * BM;
    const int wv   = tid >> 6;       // wave 0..3 -> experts wv*16..wv*16+15
    const int lane = tid & 63;
    const int r    = lane & 15;      // A-row / B-col free index
    const int kq   = lane >> 4;      // k-slot within K=4
    const int swz  = r & 7;          // read-side swizzle key

    // ---- C/D layout self-calibration (2 probe MFMAs) ----
    f64x4 rowp = {0., 0., 0., 0.};
    f64x4 colp = {0., 0., 0., 0.};
    rowp = __builtin_amdgcn_mfma_f64_16x16x4f64((double)r, 1.0, rowp, 0, 0, 0);
    colp = __builtin_amdgcn_mfma_f64_16x16x4f64(1.0, (double)r, colp, 0, 0, 0);
    int drow[4], dcol[4];
#pragma unroll
    for (int j = 0; j < 4; ++j) {
        drow[j] = (int)(rowp[j] * 0.25 + 0.5);   // exact multiples of 4
        dcol[j] = (int)(colp[j] * 0.25 + 0.5);
    }

    f64x4 acc0 = {0., 0., 0., 0.};   // even K4-slots
    f64x4 acc1 = {0., 0., 0., 0.};   // odd  K4-slots

    // ---- staging: 10 segments of 1024B (256 words) per chunk ----
    // wave w owns segments {w, w+4, w+8} (waves 0,1: 3 segs; waves 2,3: 2).
    // lane l of segment s writes LDS words s*256 + l*4 .. +3, which hold:
    //   s<2  (A): row = s*8 + (l>>3), kgrp_stored = l&7 -> kgrp_orig = (l&7)^(row&7)
    //   s>=2 (B): row = (s-2)*8 + (l>>3), same swizzle
    const float* segsrc[3];          // per-lane global base (k0 = 0)
    int          segoff[3];          // LDS word offset of the segment
    int nseg = 0;
#pragma unroll
    for (int i = 0; i < 3; ++i) {
        const int s = wv + 4 * i;
        if (s < 10) {
            const int row8 = lane >> 3;
            if (s < 2) {
                const int row = s * 8 + row8;
                const int kg  = (lane & 7) ^ (row & 7);
                segsrc[i] = hid + (size_t)(bm + row) * HDIM + 4 * kg;
            } else {
                const int row = (s - 2) * 8 + row8;
                const int kg  = (lane & 7) ^ (row & 7);
                segsrc[i] = wgt + (size_t)row * HDIM + 4 * kg;
            }
            segoff[i] = s * 256;
            nseg = i + 1;
        }
    }

#define ISSUE(BUF, K0) do { \
        _Pragma("unroll") \
        for (int i = 0; i < 3; ++i) { \
            if (i < nseg) { \
                const float* src = segsrc[i] + (K0); \
                __builtin_amdgcn_global_load_lds( \
                    (const __attribute__((address_space(1))) void*)src, \
                    (__attribute__((address_space(3))) void*)&S[BUF][segoff[i]], \
                    16, 0, 0); \
            } \
        } \
    } while (0)

// dual independent chains; reads hit 32 distinct banks (2-way max, free)
#define COMPUTE(BUF) do { \
        const float* Ab = &S[BUF][(r << 5) + kq]; \
        const float* Bb = &S[BUF][512 + ((wv * 16 + r) << 5) + kq]; \
        _Pragma("unroll") \
        for (int p = 0; p < 4; ++p) { \
            const int o0 = 4 * ((2 * p) ^ swz); \
            const int o1 = 4 * ((2 * p + 1) ^ swz); \
            acc0 = __builtin_amdgcn_mfma_f64_16x16x4f64((double)Ab[o0], (double)Bb[o0], acc0, 0, 0, 0); \
            acc1 = __builtin_amdgcn_mfma_f64_16x16x4f64((double)Ab[o1], (double)Bb[o1], acc1, 0, 0, 0); \
        } \
    } while (0)

    // ---- prologue: chunk 0 -> LDS[0] ----
    ISSUE(0, 0);
    asm volatile("s_waitcnt vmcnt(0)" ::: "memory");
    __builtin_amdgcn_s_barrier();

    int cur = 0;
    for (int c = 0; c < CHUNKS; ++c) {
        // issue chunk c+1's direct-to-LDS loads (drained only at end of chunk)
        if (c + 1 < CHUNKS) ISSUE(cur ^ 1, (c + 1) * BK);
        COMPUTE(cur);                 // 8 MFMAs = 2048 pipe-cyc/SIMD of shadow
        // handoff: my ds_reads drained (lgkm), next chunk's loads landed (vm)
        asm volatile("s_waitcnt vmcnt(0) lgkmcnt(0)" ::: "memory");
        __builtin_amdgcn_s_barrier();
        cur ^= 1;
    }

#undef ISSUE
#undef COMPUTE

    // ---- epilogue: combine chains, probe-derived scatter ----
#pragma unroll
    for (int j = 0; j < 4; ++j) {
        const int row = bm + drow[j];
        const int col = wv * 16 + dcol[j];
        logits[(size_t)row * NEXP + col] = (float)(acc0[j] + acc1[j]);
    }
}

// ---------------- top-k + softmax: one wave (64 lanes) per token ----------------
__global__ __launch_bounds__(256) void topk_softmax(const float* __restrict__ logits,
                                                    float* __restrict__ out_idx,
                                                    float* __restrict__ out_w) {
    const int wave  = threadIdx.x >> 6;              // 0..3
    const int lane  = threadIdx.x & 63;
    const int token = blockIdx.x * 4 + wave;
    if (token >= TOKENS) return;

    float v = logits[(size_t)token * NEXP + lane];

    float myval = 0.f;
    int   myidx = 0;
    float max0  = 0.f;

#pragma unroll
    for (int k = 0; k < TOPK; ++k) {
        float bv = v;
        int   bi = lane;
#pragma unroll
        for (int off = 32; off > 0; off >>= 1) {   // argmax, tie -> lower index
            float ov = __shfl_xor(bv, off);
            int   oi = __shfl_xor(bi, off);
            if (ov > bv || (ov == bv && oi < bi)) { bv = ov; bi = oi; }
        }
        if (k == 0) max0 = bv;
        if (lane == k) { myval = bv; myidx = bi; }
        if (lane == bi) v = -INFINITY;
    }

    float e = (lane < TOPK) ? expf(myval - max0) : 0.f;
    float s = e;
#pragma unroll
    for (int off = 4; off > 0; off >>= 1) s += __shfl_xor(s, off);

    if (lane < TOPK) {
        size_t o = (size_t)token * TOPK + lane;
        out_idx[o] = (float)myidx;
        out_w[o]   = e / s;
    }
}

extern "C" void kernel_launch(void* const* d_in, const int* in_sizes, int n_in,
                              void* d_out, int out_size, void* d_ws, size_t ws_size,
                              hipStream_t stream) {
    const float* hid = (const float*)d_in[0];
    const float* wgt = (const float*)d_in[1];

    float* logits  = (float*)d_out;
    float* out_idx = logits + (size_t)TOKENS * NEXP;
    float* out_w   = out_idx + (size_t)TOKENS * TOPK;

    router_gemm_mfma<<<TOKENS / BM, 256, 0, stream>>>(hid, wgt, logits);
    topk_softmax<<<TOKENS / 4, 256, 0, stream>>>(logits, out_idx, out_w);
}